// Round 1
// baseline (109.450 us; speedup 1.0000x reference)
//
#include <hip/hip_runtime.h>

#define NB 32
#define CC 3
#define HH 512
#define WW 512
#define KS 25
#define PAD 12
#define RSTRIP 16

__device__ __forceinline__ float clamp01(float v) {
    return fminf(fmaxf(v, 0.0f), 1.0f);
}

// Compute normalized 1-D gaussian weights into LDS once per block.
__device__ __forceinline__ void make_weights(float* wsh) {
    int tid = threadIdx.x;
    if (tid < KS) {
        float c = (float)(tid - PAD);
        wsh[tid] = expf(-c * c / (2.0f * 9.0f * 9.0f));
    }
    __syncthreads();
    if (tid == 0) {
        float s = 0.0f;
        for (int i = 0; i < KS; ++i) s += wsh[i];
        float inv = 1.0f / s;
        for (int i = 0; i < KS; ++i) wsh[i] *= inv;
    }
    __syncthreads();
}

// Pass 1: horizontal blur. Each thread produces 8 contiguous outputs along W,
// fed by 8 aligned float4 loads covering its 32-float input window.
__global__ __launch_bounds__(256) void hblur(const float* __restrict__ x,
                                             float* __restrict__ tmp) {
    __shared__ float wsh[KS];
    make_weights(wsh);
    float wr[KS];
#pragma unroll
    for (int i = 0; i < KS; ++i) wr[i] = wsh[i];

    long gid = (long)blockIdx.x * blockDim.x + threadIdx.x;
    long row = gid >> 6;          // 64 segments of 8 per row
    int seg = (int)(gid & 63);
    const float* rp = x + row * WW;
    float* op = tmp + row * WW;
    int o0 = seg * 8;

    float acc[8] = {0, 0, 0, 0, 0, 0, 0, 0};
#pragma unroll
    for (int k = 0; k < 8; ++k) {
        int f0 = o0 - PAD + 4 * k;   // 4-aligned; fully in or fully out of [0, WW)
        float4 v = make_float4(0.f, 0.f, 0.f, 0.f);
        if (f0 >= 0 && f0 <= WW - 4) v = *(const float4*)(rp + f0);
        float vv[4] = {v.x, v.y, v.z, v.w};
#pragma unroll
        for (int e = 0; e < 4; ++e) {
            int widx = 4 * k + e;     // window index: input position o0-12+widx
#pragma unroll
            for (int j = 0; j < 8; ++j) {
                int t = widx - j;     // tap for output o0+j (compile-time pruned)
                if (t >= 0 && t < KS) acc[j] += vv[e] * wr[t];
            }
        }
    }
    float4 r0 = make_float4(acc[0], acc[1], acc[2], acc[3]);
    float4 r1 = make_float4(acc[4], acc[5], acc[6], acc[7]);
    *(float4*)(op + o0) = r0;
    *(float4*)(op + o0 + 4) = r1;
}

// Pass 2: vertical blur + clip. Each thread owns a float4 column and a strip of
// RSTRIP output rows; streams RSTRIP+KS-1 coalesced row loads into RSTRIP accs.
__global__ __launch_bounds__(256) void vblur(const float* __restrict__ tmp,
                                             float* __restrict__ out) {
    __shared__ float wsh[KS];
    make_weights(wsh);
    float wr[KS];
#pragma unroll
    for (int i = 0; i < KS; ++i) wr[i] = wsh[i];

    long gid = (long)blockIdx.x * blockDim.x + threadIdx.x;
    int col4 = (int)(gid & 127);          // consecutive lanes -> consecutive float4 cols
    long t = gid >> 7;
    int strip = (int)(t & 31);            // 512/16 strips
    long img = t >> 5;                    // N*C planes
    const float* ip = tmp + img * (long)(HH * WW) + col4 * 4;
    float* op = out + img * (long)(HH * WW) + col4 * 4;
    int r0 = strip * RSTRIP;

    float4 acc[RSTRIP];
#pragma unroll
    for (int j = 0; j < RSTRIP; ++j) acc[j] = make_float4(0.f, 0.f, 0.f, 0.f);

#pragma unroll
    for (int r = 0; r < RSTRIP + KS - 1; ++r) {
        int rr = r0 - PAD + r;
        float4 v = make_float4(0.f, 0.f, 0.f, 0.f);
        if (rr >= 0 && rr < HH) v = *(const float4*)(ip + (long)rr * WW);
#pragma unroll
        for (int j = 0; j < RSTRIP; ++j) {
            int tap = r - j;              // compile-time pruned
            if (tap >= 0 && tap < KS) {
                float wv = wr[tap];
                acc[j].x += v.x * wv;
                acc[j].y += v.y * wv;
                acc[j].z += v.z * wv;
                acc[j].w += v.w * wv;
            }
        }
    }
#pragma unroll
    for (int j = 0; j < RSTRIP; ++j) {
        float4 o;
        o.x = clamp01(acc[j].x);
        o.y = clamp01(acc[j].y);
        o.z = clamp01(acc[j].z);
        o.w = clamp01(acc[j].w);
        *(float4*)(op + (long)(r0 + j) * WW) = o;
    }
}

extern "C" void kernel_launch(void* const* d_in, const int* in_sizes, int n_in,
                              void* d_out, int out_size, void* d_ws, size_t ws_size,
                              hipStream_t stream) {
    const float* x = (const float*)d_in[0];
    float* out = (float*)d_out;
    float* tmp = (float*)d_ws;   // needs NB*CC*HH*WW*4 = ~100.7 MB

    // Pass 1: NB*CC*HH rows, 64 threads-worth of segments each
    long threads1 = (long)NB * CC * HH * (WW / 8);   // 3,145,728
    hblur<<<(int)(threads1 / 256), 256, 0, stream>>>(x, tmp);

    // Pass 2: NB*CC planes * 128 float4-cols * 32 strips
    long threads2 = (long)NB * CC * (WW / 4) * (HH / RSTRIP);  // 393,216
    vblur<<<(int)(threads2 / 256), 256, 0, stream>>>(tmp, out);
}

// Round 2
// 52.971 us; speedup vs baseline: 2.0662x; 2.0662x over previous
//
#include <hip/hip_runtime.h>

#define NB 32
#define CC 3
#define HH 512
#define WW 512
#define KS 25
#define PAD 12
#define HT 16                 // output rows per block (full 512-wide strip)
#define LDSW 536              // 12 halo + 512 + 12 halo floats per LDS row

__device__ __forceinline__ float clamp01(float v) {
    return fminf(fmaxf(v, 0.0f), 1.0f);
}

__global__ __launch_bounds__(256) void gblur_fused(const float* __restrict__ x,
                                                   float* __restrict__ out) {
    __shared__ float wsh[KS];
    __shared__ float tile[HT * LDSW];   // 34,304 B -> 4 blocks/CU

    int tid = threadIdx.x;

    // ---- weights: 25 expf lanes, serial normalize by t0 (once per block) ----
    if (tid < KS) {
        float c = (float)(tid - PAD);
        wsh[tid] = expf(-c * c / (2.0f * 9.0f * 9.0f));
    }
    __syncthreads();
    if (tid == 0) {
        float s = 0.0f;
        for (int i = 0; i < KS; ++i) s += wsh[i];
        float inv = 1.0f / s;
        for (int i = 0; i < KS; ++i) wsh[i] *= inv;
    }
    // zero the left/right LDS halos (independent of wsh; covered by next sync)
    for (int i = tid; i < HT * 2 * PAD; i += 256) {
        int r = i / (2 * PAD);
        int k = i - r * (2 * PAD);
        tile[r * LDSW + (k < PAD ? k : 512 + k)] = 0.0f;
    }
    __syncthreads();

    float wr[KS];
#pragma unroll
    for (int i = 0; i < KS; ++i) wr[i] = wsh[i];   // LDS broadcast reads

    // ---- block mapping with bijective XCD swizzle (3072 % 8 == 0) ----
    int b = blockIdx.x;
    const int nwg = NB * CC * (HH / HT);   // 3072
    int per = nwg >> 3;
    int swz = (b & 7) * per + (b >> 3);
    int plane = swz >> 5;                  // 32 strips per plane
    int strip = swz & 31;
    int r0 = strip * HT;

    const float* ibase = x + (long)plane * (HH * WW);
    float*       obase = out + (long)plane * (HH * WW);

    // ---- vertical stage: thread = (float4 col, 8-row group) ----
    int col4 = tid & 127;                  // consecutive lanes -> coalesced f4
    int rg = (tid >> 7) * 8;               // 0 or 8; wave-uniform
    const float* ip = ibase + col4 * 4;

    float4 acc[8];
#pragma unroll
    for (int j = 0; j < 8; ++j) acc[j] = make_float4(0.f, 0.f, 0.f, 0.f);

#pragma unroll
    for (int r = 0; r < 8 + KS - 1; ++r) {          // 32 input rows
        int rr = r0 + rg - PAD + r;
        float4 v = make_float4(0.f, 0.f, 0.f, 0.f);
        if (rr >= 0 && rr < HH)                      // wave-uniform branch
            v = *(const float4*)(ip + (long)rr * WW);
#pragma unroll
        for (int j = 0; j < 8; ++j) {
            int t = r - j;                           // compile-time pruned
            if (t >= 0 && t < KS) {
                float wv = wr[t];
                acc[j].x += v.x * wv; acc[j].y += v.y * wv;
                acc[j].z += v.z * wv; acc[j].w += v.w * wv;
            }
        }
    }
#pragma unroll
    for (int j = 0; j < 8; ++j)
        *(float4*)&tile[(rg + j) * LDSW + PAD + col4 * 4] = acc[j];

    __syncthreads();

    // ---- horizontal stage + clip: wave per row, lane owns f4 cols l, l+64 ----
    int lane = tid & 63;
    int wv = tid >> 6;
#pragma unroll
    for (int it = 0; it < HT / 4; ++it) {
        int rr = wv + it * 4;
        const float* lrow = &tile[rr * LDSW];
#pragma unroll
        for (int half = 0; half < 2; ++half) {
            int c = lane + half * 64;
            float av[28];
#pragma unroll
            for (int q = 0; q < 7; ++q) {            // 7x ds_read_b128, 16B lane stride
                float4 vq = *(const float4*)(lrow + 4 * c + 4 * q);
                av[4*q+0] = vq.x; av[4*q+1] = vq.y; av[4*q+2] = vq.z; av[4*q+3] = vq.w;
            }
            float o[4] = {0.f, 0.f, 0.f, 0.f};
#pragma unroll
            for (int t = 0; t < KS; ++t) {
                float wt = wr[t];
#pragma unroll
                for (int j = 0; j < 4; ++j) o[j] += av[t + j] * wt;
            }
            float4 ov = make_float4(clamp01(o[0]), clamp01(o[1]),
                                    clamp01(o[2]), clamp01(o[3]));
            *(float4*)(obase + (long)(r0 + rr) * WW + 4 * c) = ov;  // coalesced
        }
    }
}

extern "C" void kernel_launch(void* const* d_in, const int* in_sizes, int n_in,
                              void* d_out, int out_size, void* d_ws, size_t ws_size,
                              hipStream_t stream) {
    const float* x = (const float*)d_in[0];
    float* out = (float*)d_out;
    const int nwg = NB * CC * (HH / HT);   // 3072 blocks
    gblur_fused<<<nwg, 256, 0, stream>>>(x, out);
}